// Round 1
// baseline (100.875 us; speedup 1.0000x reference)
//
#include <hip/hip_runtime.h>
#include <hip/hip_cooperative_groups.h>

namespace cg = cooperative_groups;

// steps = 65536, channels = 6, state = [pos(6), vel(6)]
// Closed form of the scan:
//   S_t = sum_{i<=t} a_i        (per channel)
//   W_t = sum_{i<=t} i * a_i    (per channel)
//   vel[t] = v0 + dt*S_t
//   pos[t] = p0 + dt*(t+1)*v0 + dt^2*((t+0.5)*S_t - W_t)
// Output layout: states [65536,12] flat, then actions [65536,6] flat.
//
// Single cooperative kernel. Phase 1: stage the block's 256-step action chunk
// into LDS (coalesced float4), write the actions passthrough, wave-reduce the
// per-(block,channel) partial sums (sA, sW) into a static __device__ array
// (NOT d_ws — the harness re-poisons the 256 MiB workspace inside the timed
// region at ~40 us/iter; we must never touch it). Phase 2 after grid.sync():
// cross-block exclusive prefix (256 partials, 4/lane, wave-reduced), then the
// 4x 64-lane inclusive scans (lane <-> timestep) and coalesced state writeout.
// The LDS-staged chunk survives the grid sync, so actions are read from HBM
// exactly once. Every g_bsum slot is rewritten before the sync on every
// launch, so there is no cross-iteration state dependence.

#define STEPS   65536
#define NCH     6
#define STATE   12
#define NB      256
#define CHUNK   (STEPS / NB)        // 256 steps per block
#define BLK     (NCH * 64)          // 384 threads = 6 waves; wave w <-> channel w
#define ACT_OFF (STEPS * STATE)     // float offset of actions region in out

__device__ double g_bsum[NB * NCH * 2];   // 24 KiB static scratch (replaces d_ws)

__global__ __launch_bounds__(BLK) void k_fused(const float4* __restrict__ act4,
                                               const float* __restrict__ x,
                                               float* __restrict__ out) {
    __shared__ float sIn[CHUNK * NCH];      // 6 KiB  — action chunk, persists across grid sync
    __shared__ float sOut[CHUNK * STATE];   // 12 KiB — state chunk for coalesced writeout
    const int b = blockIdx.x, tid = threadIdx.x;

    // Coalesced stage-in + actions passthrough (coalesced float4 store).
    float4 v = act4[b * (CHUNK * NCH / 4) + tid];
    ((float4*)(out + ACT_OFF))[b * (CHUNK * NCH / 4) + tid] = v;
    ((float4*)sIn)[tid] = v;
    __syncthreads();

    const int c = tid >> 6, lane = tid & 63;

    // ---- Phase 1: per-(block,channel) partials ----
    {
        double sA = 0.0, sW = 0.0;
#pragma unroll
        for (int k = 0; k < 4; ++k) {
            const int   tl = k * 64 + lane;
            const float a  = sIn[tl * NCH + c];
            sA += (double)a;
            sW += (double)(b * CHUNK + tl) * (double)a;
        }
#pragma unroll
        for (int off = 32; off > 0; off >>= 1) {
            sA += __shfl_down(sA, off, 64);
            sW += __shfl_down(sW, off, 64);
        }
        if (lane == 0) {
            g_bsum[(b * NCH + c) * 2 + 0] = sA;
            g_bsum[(b * NCH + c) * 2 + 1] = sW;
        }
    }

    cg::this_grid().sync();

    // ---- Phase 2: cross-block exclusive prefix for this channel ----
    double offA, offW;
    {
        double vA = 0.0, vW = 0.0;
#pragma unroll
        for (int k = 0; k < 4; ++k) {
            const int idx = k * 64 + lane;
            if (idx < b) {
                vA += g_bsum[(idx * NCH + c) * 2 + 0];
                vW += g_bsum[(idx * NCH + c) * 2 + 1];
            }
        }
#pragma unroll
        for (int off = 32; off > 0; off >>= 1) {
            vA += __shfl_down(vA, off, 64);
            vW += __shfl_down(vW, off, 64);
        }
        offA = __shfl(vA, 0, 64);
        offW = __shfl(vW, 0, 64);
    }

    const double dt  = (double)0.1f;   // match float32(0.1) bit pattern
    const double dt2 = dt * dt;
    const double p0  = (double)x[c];
    const double v0  = (double)x[NCH + c];

    double accA = offA, accW = offW;   // running totals before current 64-tile
#pragma unroll
    for (int k = 0; k < 4; ++k) {
        const int   tl = k * 64 + lane;
        const int   t  = b * CHUNK + tl;
        const float a  = sIn[tl * NCH + c];
        double iA = (double)a;
        double iW = (double)t * (double)a;
        // Inclusive 64-lane scan (lane <-> t, stride 1).
#pragma unroll
        for (int off = 1; off < 64; off <<= 1) {
            const double uA = __shfl_up(iA, off, 64);
            const double uW = __shfl_up(iW, off, 64);
            if (lane >= off) { iA += uA; iW += uW; }
        }
        const double runA = accA + iA;
        const double runW = accW + iW;
        const double vel = v0 + dt * runA;
        const double pos = p0 + dt * (double)(t + 1) * v0
                         + dt2 * (((double)t + 0.5) * runA - runW);
        sOut[tl * STATE + c]       = (float)pos;
        sOut[tl * STATE + NCH + c] = (float)vel;
        accA += __shfl(iA, 63, 64);    // add tile total
        accW += __shfl(iW, 63, 64);
    }
    __syncthreads();

    // Coalesced writeout of the 256x12 state chunk: 768 float4, 2/thread.
    const float4* so4 = (const float4*)sOut;
    float4*       o4  = (float4*)out;
    o4[b * (CHUNK * STATE / 4) + tid]       = so4[tid];
    o4[b * (CHUNK * STATE / 4) + BLK + tid] = so4[BLK + tid];
}

extern "C" void kernel_launch(void* const* d_in, const int* in_sizes, int n_in,
                              void* d_out, int out_size, void* d_ws, size_t ws_size,
                              hipStream_t stream) {
    const float*  x    = (const float*)d_in[0];   // 12 floats: pos(6), vel(6)
    const float4* act4 = (const float4*)d_in[1];  // [65536, 6] as float4
    float*        out  = (float*)d_out;           // states(786432) + actions(393216)

    void* args[] = { (void*)&act4, (void*)&x, (void*)&out };
    hipLaunchCooperativeKernel((void*)k_fused, dim3(NB), dim3(BLK),
                               args, 0, stream);
}